// Round 5
// baseline (18964.191 us; speedup 1.0000x reference)
//
#include <hip/hip_runtime.h>

// ---------------- problem constants ----------------
#define B_ 8
#define S_ 128
#define H_ 512
#define G_ 2048   // 4H
#define MEL_ 80

// ---------------- ws layout (32-bit word offsets) ----------------
// flag groups: each flag gets its own 64B line (16-word stride)
#define FLG_DEC    0        // 72 flags
#define FLG_L0     2048     // lstm0: dir0 @ +0, dir1 @ +1024
#define FLG_L1     4096     // lstm1
#define OFF_H0S    8192                 // lstm0 h [dir][pingpong][b][512] = 16384
#define OFF_H1S    (OFF_H0S + 16384)    // 16384
#define OFF_DH     (OFF_H1S + 16384)    // dec h [b][512] = 4096
#define OFF_DIN    (OFF_DH + 4096)      // din [b][128] = 1024 (80 used/row)
#define OFF_HW     (OFF_DIN + 1024)     // (unused, layout kept) 4096
#define OFF_CTX    (OFF_HW + 4096)      // [b][1024] = 8192
#define ZERO_WORDS (OFF_CTX + 8192)     // = 58368 = 228*256
#define OFF_X0     58368                        // [bs][512]   524288
#define OFF_GX0F   (OFF_X0 + 524288)            // [bs][2048] 2097152
#define OFF_GX0B   (OFF_GX0F + 2097152)
#define OFF_H0     (OFF_GX0B + 2097152)         // [bs][1024] 1048576
#define OFF_GX1F   (OFF_H0 + 1048576)
#define OFF_GX1B   (OFF_GX1F + 2097152)
#define OFF_ENC    (OFF_GX1B + 2097152)         // [bs][1024] 1048576
#define OFF_ENCP   (OFF_ENC + 1048576)          // [bs][512]   524288

// ---------------- helpers ----------------
__device__ __forceinline__ float sigm_f(float x) {
    x = fminf(fmaxf(x, -30.f), 30.f);
    return 1.f / (1.f + __expf(-x));
}
__device__ __forceinline__ float tanh_f(float x) {
    x = fminf(fmaxf(x, -15.f), 15.f);
    float e = __expf(2.f * x);
    return (e - 1.f) / (e + 1.f);
}

// AGENT-scope (device-coherent at the LLC, cross-XCD safe) scalar access
__device__ __forceinline__ void agw_u(unsigned* p, unsigned v) {
    __hip_atomic_store(p, v, __ATOMIC_RELAXED, __HIP_MEMORY_SCOPE_AGENT);
}
__device__ __forceinline__ unsigned agr_u(const unsigned* p) {
    return __hip_atomic_load(p, __ATOMIC_RELAXED, __HIP_MEMORY_SCOPE_AGENT);
}
__device__ __forceinline__ void agw_f(float* p, float v) {
    agw_u((unsigned*)p, __float_as_uint(v));
}
__device__ __forceinline__ float agr_f(const float* p) {
    return __uint_as_float(agr_u((const unsigned*)p));
}

// full flag barrier (LSTM): arrive own line, poll nwg peers (busy poll)
__device__ __forceinline__ void flag_barrier(unsigned* flags, int wg, unsigned phase, int nwg) {
    asm volatile("s_waitcnt vmcnt(0) lgkmcnt(0)" ::: "memory");
    __syncthreads();
    if (threadIdx.x == 0)
        agw_u(flags + wg * 16, phase);
    if ((int)threadIdx.x < nwg) {
        while (agr_u(flags + threadIdx.x * 16) < phase) {}
    }
    asm volatile("s_waitcnt vmcnt(0)" ::: "memory");
    __syncthreads();
}

// arrival only (decoder partial barriers)
__device__ __forceinline__ void arrive(unsigned* flags, int wg, unsigned phase) {
    asm volatile("s_waitcnt vmcnt(0) lgkmcnt(0)" ::: "memory");
    __syncthreads();
    if (threadIdx.x == 0)
        agw_u(flags + wg * 16, phase);
}

// ---------------- zero init ----------------
__global__ __launch_bounds__(256) void zero_kernel(float* p) {
    p[blockIdx.x * 256 + threadIdx.x] = 0.f;
}

// ---------------- embedding ----------------
__global__ __launch_bounds__(256) void embed_kernel(const int* __restrict__ text,
                                                    const float* __restrict__ emb,
                                                    float* __restrict__ X) {
    int i = blockIdx.x * 256 + threadIdx.x;   // float4 id, 131072 total
    int bs = i >> 7;
    int h4 = i & 127;
    int ch = text[bs];
    ((float4*)X)[i] = ((const float4*)emb)[ch * 128 + h4];
}

// ---------------- f32 GEMM: C[M,N] = A[M,K] * W[N,K]^T + b1 (+ b2) ----------------
__global__ __launch_bounds__(256) void gemm_f32(const float* __restrict__ A, int lda,
                                                const float* __restrict__ W, int ldw,
                                                const float* __restrict__ b1,
                                                const float* __restrict__ b2,
                                                float* __restrict__ C, int ldc, int K) {
    __shared__ float As[32][68];
    __shared__ float Ws[32][68];
    int tid = threadIdx.x;
    int tx = tid & 15, ty = tid >> 4;
    int n0 = blockIdx.x * 64, m0 = blockIdx.y * 64;
    float acc[4][4] = {};
    int r  = tid >> 3;
    int c4 = (tid & 7) * 4;
    for (int k0 = 0; k0 < K; k0 += 32) {
        float4 a0 = *(const float4*)&A[(m0 + r) * lda + k0 + c4];
        float4 a1 = *(const float4*)&A[(m0 + r + 32) * lda + k0 + c4];
        float4 w0 = *(const float4*)&W[(n0 + r) * ldw + k0 + c4];
        float4 w1 = *(const float4*)&W[(n0 + r + 32) * ldw + k0 + c4];
        As[c4 + 0][r] = a0.x; As[c4 + 1][r] = a0.y; As[c4 + 2][r] = a0.z; As[c4 + 3][r] = a0.w;
        As[c4 + 0][r + 32] = a1.x; As[c4 + 1][r + 32] = a1.y; As[c4 + 2][r + 32] = a1.z; As[c4 + 3][r + 32] = a1.w;
        Ws[c4 + 0][r] = w0.x; Ws[c4 + 1][r] = w0.y; Ws[c4 + 2][r] = w0.z; Ws[c4 + 3][r] = w0.w;
        Ws[c4 + 0][r + 32] = w1.x; Ws[c4 + 1][r + 32] = w1.y; Ws[c4 + 2][r + 32] = w1.z; Ws[c4 + 3][r + 32] = w1.w;
        __syncthreads();
#pragma unroll 8
        for (int kk = 0; kk < 32; ++kk) {
            float4 av = *(const float4*)&As[kk][ty * 4];
            float4 wv = *(const float4*)&Ws[kk][tx * 4];
            acc[0][0] = fmaf(av.x, wv.x, acc[0][0]); acc[0][1] = fmaf(av.x, wv.y, acc[0][1]);
            acc[0][2] = fmaf(av.x, wv.z, acc[0][2]); acc[0][3] = fmaf(av.x, wv.w, acc[0][3]);
            acc[1][0] = fmaf(av.y, wv.x, acc[1][0]); acc[1][1] = fmaf(av.y, wv.y, acc[1][1]);
            acc[1][2] = fmaf(av.y, wv.z, acc[1][2]); acc[1][3] = fmaf(av.y, wv.w, acc[1][3]);
            acc[2][0] = fmaf(av.z, wv.x, acc[2][0]); acc[2][1] = fmaf(av.z, wv.y, acc[2][1]);
            acc[2][2] = fmaf(av.z, wv.z, acc[2][2]); acc[2][3] = fmaf(av.z, wv.w, acc[2][3]);
            acc[3][0] = fmaf(av.w, wv.x, acc[3][0]); acc[3][1] = fmaf(av.w, wv.y, acc[3][1]);
            acc[3][2] = fmaf(av.w, wv.z, acc[3][2]); acc[3][3] = fmaf(av.w, wv.w, acc[3][3]);
        }
        __syncthreads();
    }
#pragma unroll
    for (int i = 0; i < 4; ++i)
#pragma unroll
        for (int j = 0; j < 4; ++j) {
            int n = n0 + tx * 4 + j;
            int m = m0 + ty * 4 + i;
            float bias = b1[n] + (b2 ? b2[n] : 0.f);
            C[m * ldc + n] = acc[i][j] + bias;
        }
}

// ---------------- persistent bidirectional LSTM layer ----------------
__global__ __launch_bounds__(256) void lstm_kernel(const float* __restrict__ GXf,
                                                   const float* __restrict__ GXb,
                                                   const float* __restrict__ Whh_f,
                                                   const float* __restrict__ Whh_b,
                                                   float* __restrict__ Hout,
                                                   float* __restrict__ hstate,
                                                   unsigned* __restrict__ flagsL) {
    int wg = blockIdx.x;
    int dir = wg >> 6;
    int slot = wg & 63;
    const float* GX  = dir ? GXb : GXf;
    const float* Whh = dir ? Whh_b : Whh_f;
    float* hs0 = hstate + dir * 8192;   // [pingpong][b][512]
    unsigned* flags = flagsL + dir * 1024;

    int tid = threadIdx.x;
    int q  = tid >> 6;
    int jj = (tid >> 3) & 7;
    int bb = tid & 7;
    int j   = slot * 8 + jj;
    int row = q * 512 + j;
    const float* wr = Whh + row * 512;

    __shared__ float hsh[8][516];
    __shared__ float gsh[4][8][8];

    float c_reg = 0.f;

    for (int t = 0; t < 128; ++t) {
        int st = dir ? (127 - t) : t;
        const float* hsr = hs0 + (t & 1) * 4096;
        float* hsw = hs0 + ((t & 1) ^ 1) * 4096;
#pragma unroll
        for (int u = 0; u < 16; ++u) {
            int n = tid + u * 256;
            int b2 = n >> 9, k = n & 511;
            hsh[b2][k] = agr_f(hsr + b2 * 512 + k);
        }
        __syncthreads();

        float acc = GX[(bb * S_ + st) * G_ + row];
        float a0 = 0.f, a1 = 0.f, a2 = 0.f, a3 = 0.f;
#pragma unroll 8
        for (int k = 0; k < 512; k += 4) {
            float4 wv = *(const float4*)(wr + k);
            float4 hv = *(const float4*)&hsh[bb][k];
            a0 = fmaf(wv.x, hv.x, a0);
            a1 = fmaf(wv.y, hv.y, a1);
            a2 = fmaf(wv.z, hv.z, a2);
            a3 = fmaf(wv.w, hv.w, a3);
        }
        acc += (a0 + a1) + (a2 + a3);
        gsh[q][jj][bb] = acc;
        __syncthreads();

        if (q == 0) {
            float gi = gsh[0][jj][bb], gf = gsh[1][jj][bb];
            float gg = gsh[2][jj][bb], go = gsh[3][jj][bb];
            float c2 = sigm_f(gf) * c_reg + sigm_f(gi) * tanh_f(gg);
            float h2 = sigm_f(go) * tanh_f(c2);
            c_reg = c2;
            agw_f(hsw + bb * 512 + j, h2);
            Hout[(bb * S_ + st) * 1024 + dir * 512 + j] = h2;
        }
        flag_barrier(flags, slot, (unsigned)(t + 1), 64);
    }
}

// ---------------- persistent attention decoder, 72 WGs x 512 thr ----------------
// WG 0..63: gate WGs (gate-cols wg*8..wg*8+8, 4 gates, k-split over 8 q-groups)
// WG 64..71: attention WGs, one per batch: hW + scores + softmax + ctx in-WG.
// 2 partial barriers/step:
//   alpha (flag 2t+1): producers {gate 0..9 (mel/DIN), attn 64..71 (CTX)};
//                      waited on by gate WGs.
//   beta  (flag 2t+2): producers {gate 0..63 (DH)}; waited on by ALL.
union DecSMem {
    struct { float dh[8][516]; float gA[8][8][8]; float gM[4][8][8]; } a;
    struct { float dh2[512]; float hw[512]; float tmp[4][128]; float att[128]; float red[128]; } at;
    struct { float ctx[8][1028]; float din[8][132]; float gB[8][8][8]; } b;
};

__global__ __launch_bounds__(512) void decoder_kernel(float* __restrict__ ws,
                                                      const float* __restrict__ attn_W,
                                                      const float* __restrict__ attn_v,
                                                      const float* __restrict__ dec_Wih,
                                                      const float* __restrict__ dec_Whh,
                                                      const float* __restrict__ dec_bih,
                                                      const float* __restrict__ dec_bhh,
                                                      const float* __restrict__ mel_W,
                                                      const float* __restrict__ mel_b,
                                                      float* __restrict__ out, int T,
                                                      unsigned* __restrict__ flags) {
    float* ENC  = ws + OFF_ENC;
    float* ENCP = ws + OFF_ENCP;
    float* DH   = ws + OFF_DH;
    float* DIN  = ws + OFF_DIN;
    float* CTX  = ws + OFF_CTX;

    int wg = blockIdx.x;     // 0..71
    int tid = threadIdx.x;   // 0..511

    __shared__ DecSMem sm;

    // gate mapping: q-group (0..7) = (gate g = q&3, k-half kh2 = q>>2)
    int q   = tid >> 6;
    int g   = q & 3;
    int kh2 = q >> 2;
    int jj  = (tid >> 3) & 7;
    int bb  = tid & 7;
    int j   = wg * 8 + jj;                 // valid for wg<64
    int row = g * 512 + j;
    const float* whh_half = dec_Whh + (wg < 64 ? ((size_t)row * 512 + kh2 * 256) : 0);
    const float* wih_row  = dec_Wih + (wg < 64 ? ((size_t)row * 1104) : 0);
    float bias_row = (wg < 64) ? (dec_bih[row] + dec_bhh[row]) : 0.f;
    const float* mel_part = mel_W + ((wg < 10 && q < 4) ? ((wg * 8 + jj) * 512 + q * 128) : 0);

    int ab = wg - 64;        // attention batch (wg>=64)

    float c_reg = 0.f;       // decoder cell state (gate WGs, q==0)
    float hdec_acc = 0.f;    // Whh@h + bias partial-sum holder (q<4)

    for (int t = 0; t < T; ++t) {
        unsigned ph1 = (unsigned)(2 * t + 1);
        unsigned ph2 = (unsigned)(2 * t + 2);

        // ================= phase A =================
        if (wg < 64) {
            // stage DH (all batches) into LDS
#pragma unroll
            for (int u = 0; u < 8; ++u) {
                int n = tid + u * 512;
                int b2 = n >> 9, k = n & 511;
                sm.a.dh[b2][k] = agr_f(DH + b2 * 512 + k);
            }
            __syncthreads();

            // hdec k-half partial
            {
                float a0 = 0.f, a1 = 0.f, a2 = 0.f, a3 = 0.f;
                const float* hp = &sm.a.dh[bb][kh2 * 256];
#pragma unroll 8
                for (int k = 0; k < 256; k += 4) {
                    float4 wv = *(const float4*)(whh_half + k);
                    float4 hv = *(const float4*)(hp + k);
                    a0 = fmaf(wv.x, hv.x, a0); a1 = fmaf(wv.y, hv.y, a1);
                    a2 = fmaf(wv.z, hv.z, a2); a3 = fmaf(wv.w, hv.w, a3);
                }
                sm.a.gA[q][jj][bb] = (a0 + a1) + (a2 + a3);
            }
            // mel partials: WGs 0..9, q<4, rows mr = wg*8+jj, k-quarter q
            if (wg < 10 && q < 4) {
                float a0 = 0.f, a1 = 0.f, a2 = 0.f, a3 = 0.f;
                const float* hp = &sm.a.dh[bb][q * 128];
#pragma unroll 8
                for (int k = 0; k < 128; k += 4) {
                    float4 wv = *(const float4*)(mel_part + k);
                    float4 hv = *(const float4*)(hp + k);
                    a0 = fmaf(wv.x, hv.x, a0); a1 = fmaf(wv.y, hv.y, a1);
                    a2 = fmaf(wv.z, hv.z, a2); a3 = fmaf(wv.w, hv.w, a3);
                }
                sm.a.gM[q][jj][bb] = (a0 + a1) + (a2 + a3);
            }
            __syncthreads();
            if (q < 4)
                hdec_acc = sm.a.gA[q][jj][bb] + sm.a.gA[q + 4][jj][bb] + bias_row;
            if (wg < 10 && q == 0 && t > 0) {
                int mr = wg * 8 + jj;
                float mel = sm.a.gM[0][jj][bb] + sm.a.gM[1][jj][bb] +
                            sm.a.gM[2][jj][bb] + sm.a.gM[3][jj][bb] + mel_b[mr];
                agw_f(DIN + bb * 128 + mr, mel);
                out[bb * MEL_ * T + mr * T + (t - 1)] = mel;
            }
            if (wg < 10) arrive(flags, wg, ph1);

            // alpha wait: 18 producers {0..9, 64..71}
            if (tid < 18) {
                int w = (tid < 10) ? tid : (54 + tid);
                while (agr_u(flags + w * 16) < ph1) {}
            }
            asm volatile("s_waitcnt vmcnt(0)" ::: "memory");
            __syncthreads();
        } else {
            // -------- attention WG: full attention for batch ab --------
            sm.at.dh2[tid] = agr_f(DH + ab * 512 + tid);
            __syncthreads();

            // hW: row = tid (W_h = attn_W[:, :512], row stride 1536)
            {
                const float* wr = attn_W + (size_t)tid * 1536;
                float a0 = 0.f, a1 = 0.f, a2 = 0.f, a3 = 0.f;
#pragma unroll 8
                for (int k = 0; k < 512; k += 4) {
                    float4 wv = *(const float4*)(wr + k);
                    float4 hv = *(const float4*)&sm.at.dh2[k];
                    a0 = fmaf(wv.x, hv.x, a0); a1 = fmaf(wv.y, hv.y, a1);
                    a2 = fmaf(wv.z, hv.z, a2); a3 = fmaf(wv.w, hv.w, a3);
                }
                sm.at.hw[tid] = (a0 + a1) + (a2 + a3);
            }
            __syncthreads();

            // scores: s = tid&127, k-quarter kq = tid>>7
            {
                int s  = tid & 127;
                int kq = tid >> 7;
                const float* ep = ENCP + (ab * S_ + s) * 512 + kq * 128;
                const float* hp = sm.at.hw + kq * 128;
                const float* vv = attn_v + kq * 128;
                float a0 = 0.f, a1 = 0.f, a2 = 0.f, a3 = 0.f;
#pragma unroll 4
                for (int k = 0; k < 128; k += 4) {
                    float4 e4 = *(const float4*)(ep + k);
                    float4 h4 = *(const float4*)(hp + k);
                    float4 v4 = *(const float4*)(vv + k);
                    a0 = fmaf(tanh_f(e4.x + h4.x), v4.x, a0);
                    a1 = fmaf(tanh_f(e4.y + h4.y), v4.y, a1);
                    a2 = fmaf(tanh_f(e4.z + h4.z), v4.z, a2);
                    a3 = fmaf(tanh_f(e4.w + h4.w), v4.w, a3);
                }
                sm.at.tmp[kq][s] = (a0 + a1) + (a2 + a3);
            }
            __syncthreads();

            float sc = 0.f;
            if (tid < 128) {
                sc = sm.at.tmp[0][tid] + sm.at.tmp[1][tid] +
                     sm.at.tmp[2][tid] + sm.at.tmp[3][tid];
                sm.at.red[tid] = sc;
            }
            __syncthreads();
            for (int off = 64; off >= 1; off >>= 1) {
                if (tid < off) sm.at.red[tid] = fmaxf(sm.at.red[tid], sm.at.red[tid + off]);
                __syncthreads();
            }
            float mx = sm.at.red[0];
            __syncthreads();
            if (tid < 128) {
                float e = __expf(sc - mx);
                sm.at.att[tid] = e;
                sm.at.red[tid] = e;
            }
            __syncthreads();
            if (tid < 64) sm.at.red[tid] += sm.at.red[tid + 64];
            __syncthreads();
            for (int off = 32; off >= 1; off >>= 1) {
                if (tid < off) sm.at.red[tid] += sm.at.red[tid + off];
                __syncthreads();
            }
            float inv = 1.f / sm.at.red[0];

            // ctx: 2 dims/thread
            {
                int d = tid * 2;
                const float* ebase = ENC + (size_t)ab * S_ * 1024 + d;
                float acc0 = 0.f, acc1 = 0.f;
#pragma unroll 4
                for (int s2 = 0; s2 < 128; ++s2) {
                    float a = sm.at.att[s2];
                    float2 ev = *(const float2*)(ebase + (size_t)s2 * 1024);
                    acc0 = fmaf(a, ev.x, acc0);
                    acc1 = fmaf(a, ev.y, acc1);
                }
                agw_f(CTX + ab * 1024 + d,     acc0 * inv);
                agw_f(CTX + ab * 1024 + d + 1, acc1 * inv);
            }
            arrive(flags, wg, ph1);   // attn skips alpha wait, goes to beta poll
        }

        // ================= phase B (gate WGs) =================
        if (wg < 64) {
            // stage CTX + DIN
#pragma unroll
            for (int u = 0; u < 16; ++u) {
                int n = tid + u * 512;                 // 0..8191
                int b2 = n >> 10, d = n & 1023;
                sm.b.ctx[b2][d] = agr_f(CTX + n);
            }
#pragma unroll
            for (int u = 0; u < 2; ++u) {
                int n = tid + u * 512;                 // 0..1023
                int b2 = n >> 7, m = n & 127;
                sm.b.din[b2][m] = agr_f(DIN + n);
            }
            __syncthreads();

            // gates: k-half [kh2*552, +552) of Wih row (k<80 -> din, else ctx[k-80])
            {
                int lo = kh2 * 552;
                float a0 = 0.f, a1 = 0.f, a2 = 0.f, a3 = 0.f;
#pragma unroll 4
                for (int k = lo; k < lo + 552; k += 4) {
                    float4 wv = *(const float4*)(wih_row + k);
                    float4 xv = (k < 80) ? *(const float4*)&sm.b.din[bb][k]
                                         : *(const float4*)&sm.b.ctx[bb][k - 80];
                    a0 = fmaf(wv.x, xv.x, a0); a1 = fmaf(wv.y, xv.y, a1);
                    a2 = fmaf(wv.z, xv.z, a2); a3 = fmaf(wv.w, xv.w, a3);
                }
                float part = (a0 + a1) + (a2 + a3) + hdec_acc;   // hdec_acc==0 for q>=4
                sm.b.gB[q][jj][bb] = part;
            }
            __syncthreads();
            if (q == 0) {
                float gi = sm.b.gB[0][jj][bb] + sm.b.gB[4][jj][bb];
                float gf = sm.b.gB[1][jj][bb] + sm.b.gB[5][jj][bb];
                float gg = sm.b.gB[2][jj][bb] + sm.b.gB[6][jj][bb];
                float go = sm.b.gB[3][jj][bb] + sm.b.gB[7][jj][bb];
                float c2 = sigm_f(gf) * c_reg + sigm_f(gi) * tanh_f(gg);
                float h2 = sigm_f(go) * tanh_f(c2);
                c_reg = c2;
                agw_f(DH + bb * 512 + j, h2);
            }
            arrive(flags, wg, ph2);
        }

        // beta wait: all 72 WGs poll the 64 gate WGs
        if (tid < 64) {
            while (agr_u(flags + tid * 16) < ph2) {}
        }
        asm volatile("s_waitcnt vmcnt(0)" ::: "memory");
        __syncthreads();
    }

    // ---- final mel (t = T-1): WGs 0..9 ----
    if (wg < 10) {
#pragma unroll
        for (int u = 0; u < 8; ++u) {
            int n = tid + u * 512;
            int b2 = n >> 9, k = n & 511;
            sm.a.dh[b2][k] = agr_f(DH + b2 * 512 + k);
        }
        __syncthreads();
        if (q < 4) {
            float a0 = 0.f, a1 = 0.f, a2 = 0.f, a3 = 0.f;
            const float* hp = &sm.a.dh[bb][q * 128];
#pragma unroll 8
            for (int k = 0; k < 128; k += 4) {
                float4 wv = *(const float4*)(mel_part + k);
                float4 hv = *(const float4*)(hp + k);
                a0 = fmaf(wv.x, hv.x, a0); a1 = fmaf(wv.y, hv.y, a1);
                a2 = fmaf(wv.z, hv.z, a2); a3 = fmaf(wv.w, hv.w, a3);
            }
            sm.a.gM[q][jj][bb] = (a0 + a1) + (a2 + a3);
        }
        __syncthreads();
        if (q == 0) {
            int mr = wg * 8 + jj;
            float mel = sm.a.gM[0][jj][bb] + sm.a.gM[1][jj][bb] +
                        sm.a.gM[2][jj][bb] + sm.a.gM[3][jj][bb] + mel_b[mr];
            out[bb * MEL_ * T + mr * T + (T - 1)] = mel;
        }
    }
}

// ---------------- host launch ----------------
extern "C" void kernel_launch(void* const* d_in, const int* in_sizes, int n_in,
                              void* d_out, int out_size, void* d_ws, size_t ws_size,
                              hipStream_t stream) {
    const int*   text  = (const int*)d_in[0];
    const float* emb   = (const float*)d_in[2];
    const float* Wih00 = (const float*)d_in[3];
    const float* Whh00 = (const float*)d_in[4];
    const float* bih00 = (const float*)d_in[5];
    const float* bhh00 = (const float*)d_in[6];
    const float* Wih01 = (const float*)d_in[7];
    const float* Whh01 = (const float*)d_in[8];
    const float* bih01 = (const float*)d_in[9];
    const float* bhh01 = (const float*)d_in[10];
    const float* Wih10 = (const float*)d_in[11];
    const float* Whh10 = (const float*)d_in[12];
    const float* bih10 = (const float*)d_in[13];
    const float* bhh10 = (const float*)d_in[14];
    const float* Wih11 = (const float*)d_in[15];
    const float* Whh11 = (const float*)d_in[16];
    const float* bih11 = (const float*)d_in[17];
    const float* bhh11 = (const float*)d_in[18];
    const float* attn_W = (const float*)d_in[19];
    const float* attn_b = (const float*)d_in[20];
    const float* attn_v = (const float*)d_in[21];
    const float* dec_Wih = (const float*)d_in[22];
    const float* dec_Whh = (const float*)d_in[23];
    const float* dec_bih = (const float*)d_in[24];
    const float* dec_bhh = (const float*)d_in[25];
    const float* mel_W = (const float*)d_in[26];
    const float* mel_b = (const float*)d_in[27];

    float* ws = (float*)d_ws;
    unsigned* flags = (unsigned*)d_ws;
    float* out = (float*)d_out;
    int T = out_size / (B_ * MEL_);   // 200

    // zero flags + recurrent state
    zero_kernel<<<ZERO_WORDS / 256, 256, 0, stream>>>(ws);

    // embedding
    embed_kernel<<<512, 256, 0, stream>>>(text, emb, ws + OFF_X0);

    // layer0 input projections (bias folded: bih + bhh)
    gemm_f32<<<dim3(32, 16), 256, 0, stream>>>(ws + OFF_X0, 512, Wih00, 512,
                                               bih00, bhh00, ws + OFF_GX0F, 2048, 512);
    gemm_f32<<<dim3(32, 16), 256, 0, stream>>>(ws + OFF_X0, 512, Wih01, 512,
                                               bih01, bhh01, ws + OFF_GX0B, 2048, 512);
    // layer0 recurrence
    lstm_kernel<<<128, 256, 0, stream>>>(ws + OFF_GX0F, ws + OFF_GX0B, Whh00, Whh01,
                                         ws + OFF_H0, ws + OFF_H0S, flags + FLG_L0);
    // layer1 input projections
    gemm_f32<<<dim3(32, 16), 256, 0, stream>>>(ws + OFF_H0, 1024, Wih10, 1024,
                                               bih10, bhh10, ws + OFF_GX1F, 2048, 1024);
    gemm_f32<<<dim3(32, 16), 256, 0, stream>>>(ws + OFF_H0, 1024, Wih11, 1024,
                                               bih11, bhh11, ws + OFF_GX1B, 2048, 1024);
    // layer1 recurrence -> enc
    lstm_kernel<<<128, 256, 0, stream>>>(ws + OFF_GX1F, ws + OFF_GX1B, Whh10, Whh11,
                                         ws + OFF_ENC, ws + OFF_H1S, flags + FLG_L1);
    // enc_part = enc @ W_e^T + attn_b   (W_e = attn_W[:, 512:], row stride 1536)
    gemm_f32<<<dim3(8, 16), 256, 0, stream>>>(ws + OFF_ENC, 1024, attn_W + 512, 1536,
                                              attn_b, nullptr, ws + OFF_ENCP, 512, 1024);
    // decoder: 64 gate WGs + 8 attention WGs, 2 partial grid barriers / step
    decoder_kernel<<<72, 512, 0, stream>>>(ws, attn_W, attn_v, dec_Wih, dec_Whh,
                                           dec_bih, dec_bhh, mel_W, mel_b, out, T,
                                           flags + FLG_DEC);
}